// Round 4
// baseline (148.234 us; speedup 1.0000x reference)
//
#include <hip/hip_runtime.h>
#include <hip/hip_cooperative_groups.h>

namespace cg = cooperative_groups;

#define BS     16
#define NPTS   4096
#define CH     32
#define HID    16
#define NORB   64
#define SLICES 16
#define PPB    (NPTS / SLICES)   // 256 points per block

// ONE cooperative kernel: phase 1 = scan aggregation (no atomics, round-3
// stage A), grid.sync(), phase 2 = blocks 0..15 reduce slices + MLP.
// Rationale (round-3 postmortem): the two-dispatch structure cost ~14 us of
// launch gap + full-grid tail between A and B; the kernels themselves are
// ~10 us. Fusing via cooperative grid sync removes one dispatch and lets
// reducer blocks pre-stage MLP weights during phase 1.
// (Round-2 lesson: the 256 MiB ws poison fill is UNCONDITIONAL — d_ws is free.)
__global__ __launch_bounds__(256) void gigp_fused(
    const float* __restrict__ coords, // [BS][N][2][2]
    const float* __restrict__ vals,   // [BS][N][CH]
    const int*   __restrict__ mask,   // [BS][N]
    float*       __restrict__ part,   // [BS][SLICES][NORB][CH] in d_ws
    const float* __restrict__ W1, const float* __restrict__ b1,
    const float* __restrict__ W2, const float* __restrict__ b2,
    const float* __restrict__ W3, const float* __restrict__ b3,
    float*       __restrict__ out)    // [BS]
{
    __shared__ float vlds[PPB][CH];   // 32 KB, row = point, conflict-free hit reads
    __shared__ int   klds[PPB];       // mask folded in (NORB = masked-out sentinel)
    __shared__ float agg[NORB][CH + 1];   // phase 2; +1 pad
    __shared__ float wbuf[832];           // [0,512)W1 [512,528)b1 [528,784)W2
                                          // [784,800)b2 [800,816)W3 [816]b3
    const int tid   = threadIdx.x;
    const int bid   = blockIdx.x;
    const int b     = bid >> 4;           // / SLICES
    const int slice = bid & (SLICES - 1);
    const size_t gbase = (size_t)b * NPTS + slice * PPB;

    // ---- phase 1: aggregate this block's 256-point slice ----
    const float4* v4  = (const float4*)vals + gbase * (CH / 4);
    float4*       vl4 = (float4*)&vlds[0][0];
    #pragma unroll
    for (int i = 0; i < PPB * CH / (4 * 256); ++i)   // 8 iters
        vl4[tid + i * 256] = v4[tid + i * 256];

    {   // keys: one per thread
        const size_t gi = gbase + tid;
        const int k = (int)coords[gi * 4 + 3];       // coords[b][n][1][1]
        klds[tid] = mask[gi] ? k : NORB;             // sentinel never matches
    }
    __syncthreads();

    const int myk  = tid >> 2;
    const int c0   = (tid & 3) * 8;
    const int lane = tid & 63;
    // wave w owns contiguous orbit range [wo, wo+16): cheap scalar pre-filter
    const int wo_s = __builtin_amdgcn_readfirstlane((tid >> 6) << 4);

    float acc[8] = {0, 0, 0, 0, 0, 0, 0, 0};

    for (int base = 0; base < PPB; base += 64) {
        const int kreg = klds[base + lane];          // 64 keys into wave regs
        #pragma unroll 8
        for (int j = 0; j < 64; ++j) {
            const int kn = __builtin_amdgcn_readlane(kreg, j);  // SGPR
            if ((unsigned)(kn - wo_s) < 16u) {       // scalar range test
                if (kn == myk) {                     // exactly 4 lanes hit
                    const float4 u0 = *(const float4*)&vlds[base + j][c0];
                    const float4 u1 = *(const float4*)&vlds[base + j][c0 + 4];
                    acc[0] += u0.x; acc[1] += u0.y; acc[2] += u0.z; acc[3] += u0.w;
                    acc[4] += u1.x; acc[5] += u1.y; acc[6] += u1.z; acc[7] += u1.w;
                }
            }
        }
    }

    // deterministic partial store: thread owns float4 pair {fi, fi+1}
    {
        float4* dst = (float4*)(part + ((size_t)b * SLICES + slice) * NORB * CH);
        const int fi = myk * 8 + (tid & 3) * 2;
        dst[fi]     = make_float4(acc[0], acc[1], acc[2], acc[3]);
        dst[fi + 1] = make_float4(acc[4], acc[5], acc[6], acc[7]);
    }

    // reducer blocks pre-stage MLP weights during phase 1 (hidden under the
    // other 240 blocks' tail; avoids cold serial weight loads after the sync)
    if (bid < BS) {
        for (int i = tid; i < 817; i += 256) {
            float w;
            if      (i < 512) w = W1[i];
            else if (i < 528) w = b1[i - 512];
            else if (i < 784) w = W2[i - 528];
            else if (i < 800) w = b2[i - 784];
            else if (i < 816) w = W3[i - 800];
            else              w = b3[0];
            wbuf[i] = w;
        }
    }

    cg::this_grid().sync();   // part fully written & visible device-wide

    // ---- phase 2: blocks 0..15 reduce 16 slices + MLP ----
    if (bid >= BS) return;

    const float4* src = (const float4*)(part + (size_t)bid * SLICES * NORB * CH);
    float4 a0 = make_float4(0.f, 0.f, 0.f, 0.f);
    float4 a1 = make_float4(0.f, 0.f, 0.f, 0.f);
    #pragma unroll
    for (int s = 0; s < SLICES; ++s) {   // 32 independent float4 loads in flight
        const float4 t0 = src[s * (NORB * CH / 4) + tid];
        const float4 t1 = src[s * (NORB * CH / 4) + tid + 256];
        a0.x += t0.x; a0.y += t0.y; a0.z += t0.z; a0.w += t0.w;
        a1.x += t1.x; a1.y += t1.y; a1.z += t1.z; a1.w += t1.w;
    }
    {
        const int e0 = tid, e1 = tid + 256;
        const int k0 = e0 >> 3, cc0 = (e0 & 7) * 4;
        const int k1 = e1 >> 3, cc1 = (e1 & 7) * 4;
        agg[k0][cc0 + 0] = a0.x; agg[k0][cc0 + 1] = a0.y;
        agg[k0][cc0 + 2] = a0.z; agg[k0][cc0 + 3] = a0.w;
        agg[k1][cc1 + 0] = a1.x; agg[k1][cc1 + 1] = a1.y;
        agg[k1][cc1 + 2] = a1.z; agg[k1][cc1 + 3] = a1.w;
    }
    __syncthreads();

    if (tid < NORB) {
        const int k = tid;
        const float* Wl1 = wbuf;
        const float* bl1 = wbuf + 512;
        const float* Wl2 = wbuf + 528;
        const float* bl2 = wbuf + 784;
        const float* Wl3 = wbuf + 800;
        const float  bl3 = wbuf[816];

        float chsum = 0.0f;
        #pragma unroll
        for (int cc = 0; cc < CH; ++cc) chsum += agg[k][cc];

        float h1[HID];
        #pragma unroll
        for (int j = 0; j < HID; ++j) h1[j] = bl1[j];
        #pragma unroll
        for (int cc = 0; cc < CH; ++cc) {
            const float x = agg[k][cc];
            #pragma unroll
            for (int j = 0; j < HID; ++j)
                h1[j] += x * Wl1[cc * HID + j];
        }
        #pragma unroll
        for (int j = 0; j < HID; ++j) h1[j] = h1[j] > 0.0f ? h1[j] : 0.0f;

        float h2[HID];
        #pragma unroll
        for (int j = 0; j < HID; ++j) h2[j] = bl2[j];
        #pragma unroll
        for (int i = 0; i < HID; ++i) {
            const float x = h1[i];
            #pragma unroll
            for (int j = 0; j < HID; ++j)
                h2[j] += x * Wl2[i * HID + j];
        }
        float o = bl3;
        #pragma unroll
        for (int i = 0; i < HID; ++i) {
            const float x = h2[i] > 0.0f ? h2[i] : 0.0f;
            o += x * Wl3[i];
        }
        o = (chsum == 0.0f) ? 0.0f : o;

        #pragma unroll
        for (int off = 32; off > 0; off >>= 1)
            o += __shfl_down(o, off);
        if (k == 0) out[bid] = o;
    }
}

extern "C" void kernel_launch(void* const* d_in, const int* in_sizes, int n_in,
                              void* d_out, int out_size, void* d_ws, size_t ws_size,
                              hipStream_t stream) {
    const float* coords = (const float*)d_in[0];
    const float* vals   = (const float*)d_in[1];
    const int*   mask   = (const int*)d_in[2];
    const float* W1     = (const float*)d_in[3];
    const float* b1     = (const float*)d_in[4];
    const float* W2     = (const float*)d_in[5];
    const float* b2     = (const float*)d_in[6];
    const float* W3     = (const float*)d_in[7];
    const float* b3     = (const float*)d_in[8];
    float* out  = (float*)d_out;
    float* part = (float*)d_ws;   // 2 MB, fully overwritten each launch

    void* args[] = {(void*)&coords, (void*)&vals, (void*)&mask, (void*)&part,
                    (void*)&W1, (void*)&b1, (void*)&W2, (void*)&b2,
                    (void*)&W3, (void*)&b3, (void*)&out};
    hipLaunchCooperativeKernel((const void*)gigp_fused,
                               dim3(BS * SLICES), dim3(256), args, 0, stream);
}

// Round 5
// 113.085 us; speedup vs baseline: 1.3108x; 1.3108x over previous
//
#include <hip/hip_runtime.h>

#define BS     16
#define NPTS   4096
#define CH     32
#define HID    16
#define NORB   64
#define SLICES 16
#define PPB    (NPTS / SLICES)   // 256 points per block

// Two-word, byte-distinct sentinels: a byte-patterned poison fill (or any
// single repeated value) cannot match both words.
#define SENT_A 0x1F2E3D4Cu
#define SENT_B 0x5A6B7C8Du

// ONE regular dispatch, no grid sync (round-4 postmortem: cg::grid.sync cost
// ~40 us AND hipLaunchCooperativeKernel added ~28 us of per-iter launch
// overhead; round-3's two dispatches cost ~20 us of launch/gap for ~5 us of
// kernel work). Producer/consumer inside one grid instead:
//   - 256 blocks (1/CU), block (b,slice) scan-aggregates its 256 points
//     (round-3 register scan, zero atomics), stores partials, then publishes
//     a device-scope release flag.
//   - the 16 slice==0 blocks then spin-acquire on their batch's 15 flags
//     (their CU is idle anyway), reduce the 16 partials and run the MLP.
// Co-residency: 256 blocks <= 256 CUs -> spin cannot deadlock.
__global__ __launch_bounds__(256) void gigp_onepass(
    const float* __restrict__ coords, // [BS][N][2][2]
    const float* __restrict__ vals,   // [BS][N][CH]
    const int*   __restrict__ mask,   // [BS][N]
    float*       __restrict__ part,   // [BS][SLICES][NORB][CH] in d_ws
    unsigned*               flags,    // [BS*SLICES][2] in d_ws (after part)
    const float* __restrict__ W1, const float* __restrict__ b1,
    const float* __restrict__ W2, const float* __restrict__ b2,
    const float* __restrict__ W3, const float* __restrict__ b3,
    float*       __restrict__ out)    // [BS]
{
    __shared__ float vlds[PPB][CH];     // 32 KB, row = point
    __shared__ int   klds[PPB];         // mask folded (NORB = sentinel)
    __shared__ float agg[NORB][CH + 1]; // consumer phase; +1 pad
    __shared__ float wbuf[832];         // [0,512)W1 [512,528)b1 [528,784)W2
                                        // [784,800)b2 [800,816)W3 [816]b3
    const int tid   = threadIdx.x;
    const int bid   = blockIdx.x;
    const int b     = bid >> 4;           // / SLICES
    const int slice = bid & (SLICES - 1);
    const size_t gbase = (size_t)b * NPTS + slice * PPB;

    // ---- producer: stage slice into LDS ----
    const float4* v4  = (const float4*)vals + gbase * (CH / 4);
    float4*       vl4 = (float4*)&vlds[0][0];
    #pragma unroll
    for (int i = 0; i < PPB * CH / (4 * 256); ++i)   // 8 iters
        vl4[tid + i * 256] = v4[tid + i * 256];

    {   // keys: one per thread
        const size_t gi = gbase + tid;
        const int k = (int)coords[gi * 4 + 3];       // coords[b][n][1][1]
        klds[tid] = mask[gi] ? k : NORB;
    }

    // consumer blocks pre-stage MLP weights, overlapped with vals staging
    if (slice == 0) {
        for (int i = tid; i < 817; i += 256) {
            float w;
            if      (i < 512) w = W1[i];
            else if (i < 528) w = b1[i - 512];
            else if (i < 784) w = W2[i - 528];
            else if (i < 800) w = b2[i - 784];
            else if (i < 816) w = W3[i - 800];
            else              w = b3[0];
            wbuf[i] = w;
        }
    }
    __syncthreads();

    // ---- register scan: thread owns (orbit tid>>2, channels (tid&3)*8..+8) ----
    const int myk  = tid >> 2;
    const int c0   = (tid & 3) * 8;
    const int lane = tid & 63;
    const int wo_s = __builtin_amdgcn_readfirstlane((tid >> 6) << 4);

    float acc[8] = {0, 0, 0, 0, 0, 0, 0, 0};

    for (int base = 0; base < PPB; base += 64) {
        const int kreg = klds[base + lane];          // 64 keys into wave regs
        #pragma unroll 8
        for (int j = 0; j < 64; ++j) {
            const int kn = __builtin_amdgcn_readlane(kreg, j);  // SGPR
            if ((unsigned)(kn - wo_s) < 16u) {       // scalar range pre-filter
                if (kn == myk) {                     // exactly 4 lanes hit
                    const float4 u0 = *(const float4*)&vlds[base + j][c0];
                    const float4 u1 = *(const float4*)&vlds[base + j][c0 + 4];
                    acc[0] += u0.x; acc[1] += u0.y; acc[2] += u0.z; acc[3] += u0.w;
                    acc[4] += u1.x; acc[5] += u1.y; acc[6] += u1.z; acc[7] += u1.w;
                }
            }
        }
    }

    // deterministic partial store
    {
        float4* dst = (float4*)(part + ((size_t)b * SLICES + slice) * NORB * CH);
        const int fi = myk * 8 + (tid & 3) * 2;
        dst[fi]     = make_float4(acc[0], acc[1], acc[2], acc[3]);
        dst[fi + 1] = make_float4(acc[4], acc[5], acc[6], acc[7]);
    }

    // publish: barrier drains the block's stores (vmcnt0), agent fence writes
    // back L2, release stores make the flag + partials device-visible.
    __syncthreads();
    if (tid == 0) {
        __threadfence();
        __hip_atomic_store(&flags[bid * 2 + 0], SENT_A,
                           __ATOMIC_RELEASE, __HIP_MEMORY_SCOPE_AGENT);
        __hip_atomic_store(&flags[bid * 2 + 1], SENT_B,
                           __ATOMIC_RELEASE, __HIP_MEMORY_SCOPE_AGENT);
    }

    if (slice != 0) return;

    // ---- consumer: wait for the other 15 slices of batch b ----
    if (tid < SLICES - 1) {
        unsigned* fa = &flags[(b * SLICES + tid + 1) * 2 + 0];
        unsigned* fb = &flags[(b * SLICES + tid + 1) * 2 + 1];
        while (__hip_atomic_load(fa, __ATOMIC_ACQUIRE,
                                 __HIP_MEMORY_SCOPE_AGENT) != SENT_A)
            __builtin_amdgcn_s_sleep(1);
        while (__hip_atomic_load(fb, __ATOMIC_ACQUIRE,
                                 __HIP_MEMORY_SCOPE_AGENT) != SENT_B)
            __builtin_amdgcn_s_sleep(1);
    }
    __syncthreads();   // acquire-invalidate done before any partial load below

    // ---- reduce 16 slices + MLP (round-3 stage B body) ----
    const float4* src = (const float4*)(part + (size_t)b * SLICES * NORB * CH);
    float4 a0 = make_float4(0.f, 0.f, 0.f, 0.f);
    float4 a1 = make_float4(0.f, 0.f, 0.f, 0.f);
    #pragma unroll
    for (int s = 0; s < SLICES; ++s) {
        const float4 t0 = src[s * (NORB * CH / 4) + tid];
        const float4 t1 = src[s * (NORB * CH / 4) + tid + 256];
        a0.x += t0.x; a0.y += t0.y; a0.z += t0.z; a0.w += t0.w;
        a1.x += t1.x; a1.y += t1.y; a1.z += t1.z; a1.w += t1.w;
    }
    {
        const int e0 = tid, e1 = tid + 256;
        const int k0 = e0 >> 3, cc0 = (e0 & 7) * 4;
        const int k1 = e1 >> 3, cc1 = (e1 & 7) * 4;
        agg[k0][cc0 + 0] = a0.x; agg[k0][cc0 + 1] = a0.y;
        agg[k0][cc0 + 2] = a0.z; agg[k0][cc0 + 3] = a0.w;
        agg[k1][cc1 + 0] = a1.x; agg[k1][cc1 + 1] = a1.y;
        agg[k1][cc1 + 2] = a1.z; agg[k1][cc1 + 3] = a1.w;
    }
    __syncthreads();

    if (tid < NORB) {
        const int k = tid;
        const float* Wl1 = wbuf;
        const float* bl1 = wbuf + 512;
        const float* Wl2 = wbuf + 528;
        const float* bl2 = wbuf + 784;
        const float* Wl3 = wbuf + 800;
        const float  bl3 = wbuf[816];

        float chsum = 0.0f;
        #pragma unroll
        for (int cc = 0; cc < CH; ++cc) chsum += agg[k][cc];

        float h1[HID];
        #pragma unroll
        for (int j = 0; j < HID; ++j) h1[j] = bl1[j];
        #pragma unroll
        for (int cc = 0; cc < CH; ++cc) {
            const float x = agg[k][cc];
            #pragma unroll
            for (int j = 0; j < HID; ++j)
                h1[j] += x * Wl1[cc * HID + j];
        }
        #pragma unroll
        for (int j = 0; j < HID; ++j) h1[j] = h1[j] > 0.0f ? h1[j] : 0.0f;

        float h2[HID];
        #pragma unroll
        for (int j = 0; j < HID; ++j) h2[j] = bl2[j];
        #pragma unroll
        for (int i = 0; i < HID; ++i) {
            const float x = h1[i];
            #pragma unroll
            for (int j = 0; j < HID; ++j)
                h2[j] += x * Wl2[i * HID + j];
        }
        float o = bl3;
        #pragma unroll
        for (int i = 0; i < HID; ++i) {
            const float x = h2[i] > 0.0f ? h2[i] : 0.0f;
            o += x * Wl3[i];
        }
        o = (chsum == 0.0f) ? 0.0f : o;

        #pragma unroll
        for (int off = 32; off > 0; off >>= 1)
            o += __shfl_down(o, off);
        if (k == 0) out[b] = o;
    }
}

extern "C" void kernel_launch(void* const* d_in, const int* in_sizes, int n_in,
                              void* d_out, int out_size, void* d_ws, size_t ws_size,
                              hipStream_t stream) {
    const float* coords = (const float*)d_in[0];
    const float* vals   = (const float*)d_in[1];
    const int*   mask   = (const int*)d_in[2];
    const float* W1     = (const float*)d_in[3];
    const float* b1     = (const float*)d_in[4];
    const float* W2     = (const float*)d_in[5];
    const float* b2     = (const float*)d_in[6];
    const float* W3     = (const float*)d_in[7];
    const float* b3     = (const float*)d_in[8];
    float* out  = (float*)d_out;
    float*    part  = (float*)d_ws;   // 2 MB, fully overwritten each launch
    unsigned* flags = (unsigned*)((char*)d_ws +
                      (size_t)BS * SLICES * NORB * CH * sizeof(float));
    // flags are NOT pre-zeroed: two-word distinct-byte sentinels make a
    // collision with the (byte-patterned) workspace poison impossible.

    gigp_onepass<<<BS * SLICES, 256, 0, stream>>>(coords, vals, mask,
                                                  part, flags,
                                                  W1, b1, W2, b2, W3, b3, out);
}

// Round 6
// 101.230 us; speedup vs baseline: 1.4643x; 1.1171x over previous
//
#include <hip/hip_runtime.h>

#define BS     16
#define NPTS   4096
#define CH     32
#define HID    16
#define NORB   64
#define SLICES 16
#define PPB    (NPTS / SLICES)   // 256 points per block

// Best measured structure: two regular dispatches (96.7/98.0 us vs 113-232 us
// for every single-dispatch variant — coop grid.sync ~40us, agent-scope
// release/acquire publish ~30us, LDS atomics ~160us). The ~73us of
// unconditional reset fills dominates dur; controllable part is ~25us.

// Stage A: deterministic scan aggregation, NO atomics (round-3, measured good).
// grid = BS*SLICES = 256 blocks x 256 threads (1 block/CU).
__global__ __launch_bounds__(256) void gigp_agg(
    const float* __restrict__ coords, // [BS][N][2][2]
    const float* __restrict__ vals,   // [BS][N][CH]
    const int*   __restrict__ mask,   // [BS][N]
    float*       __restrict__ part)   // [BS][SLICES][NORB][CH]
{
    __shared__ float vlds[PPB][CH];   // 32 KB, row = point
    __shared__ int   klds[PPB];       // mask folded in (NORB = sentinel)

    const int tid   = threadIdx.x;
    const int b     = blockIdx.x >> 4;          // / SLICES
    const int slice = blockIdx.x & (SLICES - 1);
    const size_t gbase = (size_t)b * NPTS + slice * PPB;

    const float4* v4  = (const float4*)vals + gbase * (CH / 4);
    float4*       vl4 = (float4*)&vlds[0][0];
    #pragma unroll
    for (int i = 0; i < PPB * CH / (4 * 256); ++i)   // 8 iters
        vl4[tid + i * 256] = v4[tid + i * 256];

    {   // keys: one per thread
        const size_t gi = gbase + tid;
        const int k = (int)coords[gi * 4 + 3];       // coords[b][n][1][1]
        klds[tid] = mask[gi] ? k : NORB;
    }
    __syncthreads();

    const int myk  = tid >> 2;
    const int c0   = (tid & 3) * 8;
    const int lane = tid & 63;
    const int wo_s = __builtin_amdgcn_readfirstlane((tid >> 6) << 4);

    float acc[8] = {0, 0, 0, 0, 0, 0, 0, 0};

    for (int base = 0; base < PPB; base += 64) {
        const int kreg = klds[base + lane];          // 64 keys into wave regs
        #pragma unroll 8
        for (int j = 0; j < 64; ++j) {
            const int kn = __builtin_amdgcn_readlane(kreg, j);  // SGPR
            if ((unsigned)(kn - wo_s) < 16u) {       // scalar range pre-filter
                if (kn == myk) {                     // exactly 4 lanes hit
                    const float4 u0 = *(const float4*)&vlds[base + j][c0];
                    const float4 u1 = *(const float4*)&vlds[base + j][c0 + 4];
                    acc[0] += u0.x; acc[1] += u0.y; acc[2] += u0.z; acc[3] += u0.w;
                    acc[4] += u1.x; acc[5] += u1.y; acc[6] += u1.z; acc[7] += u1.w;
                }
            }
        }
    }

    float4* dst = (float4*)(part + ((size_t)b * SLICES + slice) * NORB * CH);
    const int fi = myk * 8 + (tid & 3) * 2;
    dst[fi]     = make_float4(acc[0], acc[1], acc[2], acc[3]);
    dst[fi + 1] = make_float4(acc[4], acc[5], acc[6], acc[7]);
}

// Stage B: reduce 16 slices + MLP. grid = BS blocks x 1024 threads.
// Widened vs round 3: thread (e = tid&511, half = tid>>9) sums 8 slices of
// float4 e -> 2x loads in flight, half the serial add chain; halves combined
// through one LDS pass (float4 stride -> 2-way bank aliasing, free per m136).
__global__ __launch_bounds__(1024) void gigp_mlp(
    const float* __restrict__ part, // [BS][SLICES][NORB][CH]
    const float* __restrict__ W1, const float* __restrict__ b1,
    const float* __restrict__ W2, const float* __restrict__ b2,
    const float* __restrict__ W3, const float* __restrict__ b3,
    float*       __restrict__ out)  // [BS]
{
    __shared__ float  agg[NORB][CH + 1];  // +1 pad: MLP reads bank (k+c)%32
    __shared__ float4 psum4[512];
    __shared__ float  wbuf[832];          // [0,512)W1 [512,528)b1 [528,784)W2
                                          // [784,800)b2 [800,816)W3 [816]b3
    const int b   = blockIdx.x;
    const int tid = threadIdx.x;

    if (tid < 817) {
        float w;
        if      (tid < 512) w = W1[tid];
        else if (tid < 528) w = b1[tid - 512];
        else if (tid < 784) w = W2[tid - 528];
        else if (tid < 800) w = b2[tid - 784];
        else if (tid < 816) w = W3[tid - 800];
        else                w = b3[0];
        wbuf[tid] = w;
    }

    const float4* src = (const float4*)(part + (size_t)b * SLICES * NORB * CH);
    const int e    = tid & 511;           // float4 index within [NORB][CH/4]
    const int half = tid >> 9;            // slice group: [0,8) or [8,16)
    float4 a = make_float4(0.f, 0.f, 0.f, 0.f);
    #pragma unroll
    for (int s = 0; s < 8; ++s) {         // 8 independent loads in flight
        const float4 t4 = src[(half * 8 + s) * 512 + e];
        a.x += t4.x; a.y += t4.y; a.z += t4.z; a.w += t4.w;
    }
    if (half) psum4[e] = a;
    __syncthreads();
    if (!half) {
        const float4 p = psum4[e];
        const int k = e >> 3, c = (e & 7) * 4;
        agg[k][c + 0] = a.x + p.x;
        agg[k][c + 1] = a.y + p.y;
        agg[k][c + 2] = a.z + p.z;
        agg[k][c + 3] = a.w + p.w;
    }
    __syncthreads();

    if (tid < NORB) {
        const int k = tid;
        const float* Wl1 = wbuf;
        const float* bl1 = wbuf + 512;
        const float* Wl2 = wbuf + 528;
        const float* bl2 = wbuf + 784;
        const float* Wl3 = wbuf + 800;
        const float  bl3 = wbuf[816];

        float chsum = 0.0f;
        #pragma unroll
        for (int cc = 0; cc < CH; ++cc) chsum += agg[k][cc];

        float h1[HID];
        #pragma unroll
        for (int j = 0; j < HID; ++j) h1[j] = bl1[j];
        #pragma unroll
        for (int cc = 0; cc < CH; ++cc) {
            const float x = agg[k][cc];
            #pragma unroll
            for (int j = 0; j < HID; ++j)
                h1[j] += x * Wl1[cc * HID + j];
        }
        #pragma unroll
        for (int j = 0; j < HID; ++j) h1[j] = h1[j] > 0.0f ? h1[j] : 0.0f;

        float h2[HID];
        #pragma unroll
        for (int j = 0; j < HID; ++j) h2[j] = bl2[j];
        #pragma unroll
        for (int i = 0; i < HID; ++i) {
            const float x = h1[i];
            #pragma unroll
            for (int j = 0; j < HID; ++j)
                h2[j] += x * Wl2[i * HID + j];
        }
        float o = bl3;
        #pragma unroll
        for (int i = 0; i < HID; ++i) {
            const float x = h2[i] > 0.0f ? h2[i] : 0.0f;
            o += x * Wl3[i];
        }
        o = (chsum == 0.0f) ? 0.0f : o;

        #pragma unroll
        for (int off = 32; off > 0; off >>= 1)
            o += __shfl_down(o, off);
        if (k == 0) out[b] = o;
    }
}

extern "C" void kernel_launch(void* const* d_in, const int* in_sizes, int n_in,
                              void* d_out, int out_size, void* d_ws, size_t ws_size,
                              hipStream_t stream) {
    const float* coords = (const float*)d_in[0];
    const float* vals   = (const float*)d_in[1];
    const int*   mask   = (const int*)d_in[2];
    const float* W1     = (const float*)d_in[3];
    const float* b1     = (const float*)d_in[4];
    const float* W2     = (const float*)d_in[5];
    const float* b2     = (const float*)d_in[6];
    const float* W3     = (const float*)d_in[7];
    const float* b3     = (const float*)d_in[8];
    float* out  = (float*)d_out;
    float* part = (float*)d_ws;   // 2 MB, fully overwritten by stage A

    gigp_agg<<<BS * SLICES, 256, 0, stream>>>(coords, vals, mask, part);
    gigp_mlp<<<BS, 1024, 0, stream>>>(part, W1, b1, W2, b2, W3, b3, out);
}

// Round 7
// 97.701 us; speedup vs baseline: 1.5172x; 1.0361x over previous
//
#include <hip/hip_runtime.h>

#define BS     16
#define NPTS   4096
#define CH     32
#define HID    16
#define NORB   64
#define SLICES 32
#define PPB    (NPTS / SLICES)   // 128 points per block
#define ITERS  (PPB / 32)        // 4

// REVERT to the round-0 kernel — best measured (96.7 us this session, 97.4
// prior session). Session ledger: ~73 us of dur is an UNCONDITIONAL harness
// reset (256 MiB poison fill + small memsets, proven by round 2's
// zero-workspace run), ~13-18 us is two-dispatch launch/gap overhead, and
// only ~8-10 us is kernel work. Structural alternatives all measured worse:
// scan stage A 98.0, wide stage B 101.2, producer/consumer 113.1,
// cooperative grid.sync 148.2, fused LDS-atomics 232.0.

// Stage A: per-slice LDS aggregation, deterministic float4 store of partials.
// grid = BS*SLICES blocks x 256 threads. part layout: [BS][SLICES][NORB][CH].
__global__ __launch_bounds__(256) void gigp_agg(
    const float* __restrict__ coords, // [BS][N][2][2]
    const float* __restrict__ vals,   // [BS][N][CH]
    const int*   __restrict__ mask,   // [BS][N]
    float*       __restrict__ part)   // [BS][SLICES][NORB][CH]
{
    // +1 pad: atomic phase spreads banks by (k+c)%32
    __shared__ float agg[NORB][CH + 1];

    const int tid   = threadIdx.x;
    const int b     = blockIdx.x >> 5;          // / SLICES
    const int slice = blockIdx.x & (SLICES - 1);

    for (int i = tid; i < NORB * (CH + 1); i += 256)
        (&agg[0][0])[i] = 0.0f;

    const int c4 = tid & 7;
    const int pl = tid >> 3;
    const float4* vals4 = (const float4*)vals;

    // prefetch all iterations (independent loads in flight)
    int    kk[ITERS];
    int    mm[ITERS];
    float4 vv[ITERS];
    #pragma unroll
    for (int it = 0; it < ITERS; ++it) {
        const int n  = slice * PPB + it * 32 + pl;
        const int gi = b * NPTS + n;
        kk[it] = (int)coords[(size_t)gi * 4 + 3]; // coords[b][n][1][1]
        mm[it] = mask[gi];
        vv[it] = vals4[(size_t)gi * 8 + c4];
    }
    __syncthreads();   // LDS zeroing done

    #pragma unroll
    for (int it = 0; it < ITERS; ++it) {
        if (mm[it]) {
            const int k = kk[it];
            atomicAdd(&agg[k][c4 * 4 + 0], vv[it].x);
            atomicAdd(&agg[k][c4 * 4 + 1], vv[it].y);
            atomicAdd(&agg[k][c4 * 4 + 2], vv[it].z);
            atomicAdd(&agg[k][c4 * 4 + 3], vv[it].w);
        }
    }
    __syncthreads();

    // deterministic partial store: 512 float4 per block, coalesced
    float4* dst = (float4*)(part + ((size_t)b * SLICES + slice) * NORB * CH);
    #pragma unroll
    for (int j = 0; j < 2; ++j) {
        const int e  = tid + j * 256;   // float4 index within [NORB][CH/4]
        const int k  = e >> 3;
        const int c4v = e & 7;
        float4 t;
        t.x = agg[k][c4v * 4 + 0];
        t.y = agg[k][c4v * 4 + 1];
        t.z = agg[k][c4v * 4 + 2];
        t.w = agg[k][c4v * 4 + 3];
        dst[e] = t;
    }
}

// Stage B: reduce 32 slices + MLP. grid = BS blocks x 256 threads.
__global__ __launch_bounds__(256) void gigp_mlp(
    const float* __restrict__ part, // [BS][SLICES][NORB][CH]
    const float* __restrict__ W1, const float* __restrict__ b1,
    const float* __restrict__ W2, const float* __restrict__ b2,
    const float* __restrict__ W3, const float* __restrict__ b3,
    float*       __restrict__ out)  // [BS]
{
    __shared__ float agg[NORB][CH + 1];   // pad: MLP phase reads bank (k+c)%32

    const int b   = blockIdx.x;
    const int tid = threadIdx.x;

    const float4* src = (const float4*)(part + (size_t)b * SLICES * NORB * CH);

    float4 a0 = make_float4(0.f, 0.f, 0.f, 0.f);
    float4 a1 = make_float4(0.f, 0.f, 0.f, 0.f);
    #pragma unroll
    for (int s = 0; s < SLICES; ++s) {
        const float4 t0 = src[(size_t)s * (NORB * CH / 4) + tid];
        const float4 t1 = src[(size_t)s * (NORB * CH / 4) + tid + 256];
        a0.x += t0.x; a0.y += t0.y; a0.z += t0.z; a0.w += t0.w;
        a1.x += t1.x; a1.y += t1.y; a1.z += t1.z; a1.w += t1.w;
    }
    {
        const int e0 = tid, e1 = tid + 256;
        const int k0 = e0 >> 3, c0 = (e0 & 7) * 4;
        const int k1 = e1 >> 3, c1 = (e1 & 7) * 4;
        agg[k0][c0 + 0] = a0.x; agg[k0][c0 + 1] = a0.y;
        agg[k0][c0 + 2] = a0.z; agg[k0][c0 + 3] = a0.w;
        agg[k1][c1 + 0] = a1.x; agg[k1][c1 + 1] = a1.y;
        agg[k1][c1 + 2] = a1.z; agg[k1][c1 + 3] = a1.w;
    }
    __syncthreads();

    if (tid < NORB) {
        const int k = tid;

        float chsum = 0.0f;
        #pragma unroll
        for (int cc = 0; cc < CH; ++cc) chsum += agg[k][cc];

        float h1[HID];
        #pragma unroll
        for (int j = 0; j < HID; ++j) h1[j] = b1[j];
        #pragma unroll
        for (int cc = 0; cc < CH; ++cc) {
            const float x = agg[k][cc];
            #pragma unroll
            for (int j = 0; j < HID; ++j)
                h1[j] += x * W1[cc * HID + j];
        }
        #pragma unroll
        for (int j = 0; j < HID; ++j) h1[j] = h1[j] > 0.0f ? h1[j] : 0.0f;

        float h2[HID];
        #pragma unroll
        for (int j = 0; j < HID; ++j) h2[j] = b2[j];
        #pragma unroll
        for (int i = 0; i < HID; ++i) {
            const float x = h1[i];
            #pragma unroll
            for (int j = 0; j < HID; ++j)
                h2[j] += x * W2[i * HID + j];
        }
        float o = b3[0];
        #pragma unroll
        for (int i = 0; i < HID; ++i) {
            const float x = h2[i] > 0.0f ? h2[i] : 0.0f;
            o += x * W3[i];
        }
        o = (chsum == 0.0f) ? 0.0f : o;

        // one-wave reduction over 64 orbits
        #pragma unroll
        for (int off = 32; off > 0; off >>= 1)
            o += __shfl_down(o, off);
        if (k == 0) out[b] = o;
    }
}

extern "C" void kernel_launch(void* const* d_in, const int* in_sizes, int n_in,
                              void* d_out, int out_size, void* d_ws, size_t ws_size,
                              hipStream_t stream) {
    const float* coords = (const float*)d_in[0];
    const float* vals   = (const float*)d_in[1];
    const int*   mask   = (const int*)d_in[2];
    const float* W1     = (const float*)d_in[3];
    const float* b1     = (const float*)d_in[4];
    const float* W2     = (const float*)d_in[5];
    const float* b2     = (const float*)d_in[6];
    const float* W3     = (const float*)d_in[7];
    const float* b3     = (const float*)d_in[8];
    float* out  = (float*)d_out;
    float* part = (float*)d_ws;   // 16*32*64*32*4 = 4 MB, fully written by stage A

    gigp_agg<<<BS * SLICES, 256, 0, stream>>>(coords, vals, mask, part);
    gigp_mlp<<<BS, 256, 0, stream>>>(part, W1, b1, W2, b2, W3, b3, out);
}